// Round 1
// baseline (386.112 us; speedup 1.0000x reference)
//
#include <hip/hip_runtime.h>
#include <hip/hip_bf16.h>

#define NB 4
#define NH 8
#define NL 4096
#define ND 64
#define NC 512
#define TILE_L 64
#define EPSV 1e-12f
#define COMMITV 0.0001f

typedef __attribute__((ext_vector_type(8))) short bf16x8;
typedef __attribute__((ext_vector_type(4))) float f32x4;

// round-to-nearest-even pack of two fp32 -> packed 2x bf16
__device__ __forceinline__ unsigned bfpack(float a, float b) {
    unsigned ua = __float_as_uint(a);
    unsigned ub = __float_as_uint(b);
    ua = (ua + 0x7fffu + ((ua >> 16) & 1u)) >> 16;
    ub = (ub + 0x7fffu + ((ub >> 16) & 1u)) & 0xffff0000u;
    return (ua & 0xffffu) | ub;
}

__global__ __launch_bounds__(256, 2) void kmeans_kernel(
    const float* __restrict__ x, const float* __restrict__ means,
    float* __restrict__ dists, float* __restrict__ loss)
{
    // swizzled bf16 tiles: row stride 128B, byte col offset ^= (row&7)<<4
    __shared__ alignas(16) unsigned short m_lds[NC * ND];      // 64 KB
    __shared__ alignas(16) unsigned short x_lds[TILE_L * ND];  // 8 KB
    __shared__ float msq[NC];                                  // 2 KB  (fp32 ||means_c||^2)
    __shared__ float sn2[TILE_L];                              // ||xn||^2 per row

    const int t = threadIdx.x;
    const int ltiles = NL / TILE_L;            // 64
    const int bh = blockIdx.x / ltiles;        // 0..31  (b*8+h)
    const int l0 = (blockIdx.x % ltiles) * TILE_L;
    const int h  = bh & (NH - 1);

    // ---------------- stage means[h] -> bf16 LDS (+ fp32 msq) ----------------
    const float4* mp = (const float4*)(means + (size_t)h * NC * ND);
    #pragma unroll 4
    for (int i = 0; i < 32; ++i) {
        int f4 = t + i * 256;                  // float4 index, 16 per row
        float4 v = mp[f4];
        int row = f4 >> 4;
        int q = f4 & 15;
        float ss = v.x * v.x + v.y * v.y + v.z * v.z + v.w * v.w;
        ss += __shfl_xor(ss, 1); ss += __shfl_xor(ss, 2);
        ss += __shfl_xor(ss, 4); ss += __shfl_xor(ss, 8);
        if ((t & 15) == 0) msq[row] = ss;
        unsigned lo = bfpack(v.x, v.y), hi = bfpack(v.z, v.w);
        int byte = row * 128 + ((q * 8) ^ ((row & 7) << 4));
        *(unsigned long long*)((char*)m_lds + byte) =
            (unsigned long long)lo | ((unsigned long long)hi << 32);
    }

    // ---------------- stage x tile, normalize -> bf16 LDS ----------------
    const float4* xp = (const float4*)(x + ((size_t)bh * NL + l0) * ND);
    #pragma unroll
    for (int i = 0; i < 4; ++i) {
        int f4 = t + i * 256;
        float4 v = xp[f4];
        int row = f4 >> 4;
        int q = f4 & 15;
        float ss = v.x * v.x + v.y * v.y + v.z * v.z + v.w * v.w;
        ss += __shfl_xor(ss, 1); ss += __shfl_xor(ss, 2);
        ss += __shfl_xor(ss, 4); ss += __shfl_xor(ss, 8);
        float inv = 1.0f / fmaxf(sqrtf(ss), EPSV);
        if ((t & 15) == 0) sn2[row] = ss * inv * inv;   // == ||xn||^2 (1 unless tiny norm)
        float ax = v.x * inv, ay = v.y * inv, az = v.z * inv, aw = v.w * inv;
        int byte = row * 128 + ((q * 8) ^ ((row & 7) << 4));
        *(unsigned long long*)((char*)x_lds + byte) =
            (unsigned long long)bfpack(ax, ay) | ((unsigned long long)bfpack(az, aw) << 32);
    }
    __syncthreads();

    // ---------------- MFMA: 16 rows/wave x 512 cols ----------------
    const int wave = t >> 6, lane = t & 63;
    const int r16 = lane & 15, g = lane >> 4;

    const int arow = wave * 16 + r16;          // A frag: row = lane&15, k = g*8+j
    const char* xb = (const char*)x_lds + arow * 128;
    const int sw = (arow & 7) << 4;
    bf16x8 a0 = *(const bf16x8*)(xb + ((g * 16) ^ sw));
    bf16x8 a1 = *(const bf16x8*)(xb + ((64 + g * 16) ^ sw));

    float mx[4]; int mi[4];
    #pragma unroll
    for (int r = 0; r < 4; ++r) { mx[r] = -1e30f; mi[r] = 0; }

    const size_t obase = ((size_t)bh * NL + l0 + wave * 16) * NC;

    #pragma unroll 4
    for (int c0 = 0; c0 < NC; c0 += 16) {
        int brow = c0 + r16;                   // B frag: col = lane&15, k = g*8+j
        const char* mb = (const char*)m_lds + brow * 128;
        const int bsw = (brow & 7) << 4;
        bf16x8 b0 = *(const bf16x8*)(mb + ((g * 16) ^ bsw));
        bf16x8 b1 = *(const bf16x8*)(mb + ((64 + g * 16) ^ bsw));
        f32x4 acc = {0.f, 0.f, 0.f, 0.f};
        acc = __builtin_amdgcn_mfma_f32_16x16x32_bf16(a0, b0, acc, 0, 0, 0);
        acc = __builtin_amdgcn_mfma_f32_16x16x32_bf16(a1, b1, acc, 0, 0, 0);
        // C/D: lane holds D[g*4+r][c0+r16]
        #pragma unroll
        for (int r = 0; r < 4; ++r) {
            float v = acc[r];
            dists[obase + (size_t)(g * 4 + r) * NC + (c0 + r16)] = v;
            if (v > mx[r]) { mx[r] = v; mi[r] = c0 + r16; }
        }
    }

    // argmax reduce across the 16 lanes holding the same 4 rows (same g)
    #pragma unroll
    for (int s = 1; s < 16; s <<= 1) {
        #pragma unroll
        for (int r = 0; r < 4; ++r) {
            float ov = __shfl_xor(mx[r], s);
            int   oi = __shfl_xor(mi[r], s);
            if (ov > mx[r] || (ov == mx[r] && oi < mi[r])) { mx[r] = ov; mi[r] = oi; }
        }
    }

    // loss contribution: ||xn||^2 - 2*dmax + ||m_sel||^2, per row
    float sacc = 0.f;
    #pragma unroll
    for (int r = 0; r < 4; ++r)
        sacc += sn2[wave * 16 + g * 4 + r] - 2.f * mx[r] + msq[mi[r]];
    if (r16 != 0) sacc = 0.f;                  // one lane per 16-lane group contributes
    sacc += __shfl_xor(sacc, 16);
    sacc += __shfl_xor(sacc, 32);
    if (lane == 0)
        atomicAdd(loss, sacc * (COMMITV / (float)((size_t)NB * NH * NL * ND)));
}

extern "C" void kernel_launch(void* const* d_in, const int* in_sizes, int n_in,
                              void* d_out, int out_size, void* d_ws, size_t ws_size,
                              hipStream_t stream) {
    const float* x = (const float*)d_in[0];
    const float* means = (const float*)d_in[1];
    float* dists = (float*)d_out;
    float* loss = dists + (size_t)NB * NH * NL * NC;  // second output, 1 elem

    // d_out is poisoned before every launch; zero the loss accumulator
    hipMemsetAsync(loss, 0, sizeof(float), stream);

    dim3 grid(NB * NH * (NL / TILE_L));  // 2048
    dim3 block(256);
    kmeans_kernel<<<grid, block, 0, stream>>>(x, means, dists, loss);
}

// Round 2
// 362.254 us; speedup vs baseline: 1.0659x; 1.0659x over previous
//
#include <hip/hip_runtime.h>
#include <hip/hip_bf16.h>

#define NB 4
#define NH 8
#define NL 4096
#define ND 64
#define NC 512
#define TILE_L 64
#define EPSV 1e-12f
#define COMMITV 0.0001f
#define NBLOCKS (NB * NH * (NL / TILE_L))   // 2048

typedef __attribute__((ext_vector_type(8))) short bf16x8;
typedef __attribute__((ext_vector_type(4))) float f32x4;

// round-to-nearest-even pack of two fp32 -> packed 2x bf16
__device__ __forceinline__ unsigned bfpack(float a, float b) {
    unsigned ua = __float_as_uint(a);
    unsigned ub = __float_as_uint(b);
    ua = (ua + 0x7fffu + ((ua >> 16) & 1u)) >> 16;
    ub = (ub + 0x7fffu + ((ub >> 16) & 1u)) & 0xffff0000u;
    return (ua & 0xffffu) | ub;
}

__global__ __launch_bounds__(256, 2) void kmeans_kernel(
    const float* __restrict__ x, const float* __restrict__ means,
    float* __restrict__ dists, float* __restrict__ part)
{
    // swizzled bf16 tiles: row stride 128B, byte col offset ^= (row&7)<<4
    __shared__ alignas(16) unsigned short m_lds[NC * ND];      // 64 KB
    __shared__ alignas(16) unsigned short x_lds[TILE_L * ND];  // 8 KB
    __shared__ float msq[NC];                                  // 2 KB  (fp32 ||means_c||^2)
    __shared__ float sn2[TILE_L];                              // ||xn||^2 per row
    __shared__ float wsum[4];

    const int t = threadIdx.x;
    const int ltiles = NL / TILE_L;            // 64
    const int bh = blockIdx.x / ltiles;        // 0..31  (b*8+h)
    const int l0 = (blockIdx.x % ltiles) * TILE_L;
    const int h  = bh & (NH - 1);

    // ---------------- stage means[h] -> bf16 LDS (+ fp32 msq) ----------------
    const float4* mp = (const float4*)(means + (size_t)h * NC * ND);
    #pragma unroll 4
    for (int i = 0; i < 32; ++i) {
        int f4 = t + i * 256;                  // float4 index, 16 per row
        float4 v = mp[f4];
        int row = f4 >> 4;
        int q = f4 & 15;
        float ss = v.x * v.x + v.y * v.y + v.z * v.z + v.w * v.w;
        ss += __shfl_xor(ss, 1); ss += __shfl_xor(ss, 2);
        ss += __shfl_xor(ss, 4); ss += __shfl_xor(ss, 8);
        if ((t & 15) == 0) msq[row] = ss;
        unsigned lo = bfpack(v.x, v.y), hi = bfpack(v.z, v.w);
        int byte = row * 128 + ((q * 8) ^ ((row & 7) << 4));
        *(unsigned long long*)((char*)m_lds + byte) =
            (unsigned long long)lo | ((unsigned long long)hi << 32);
    }

    // ---------------- stage x tile, normalize -> bf16 LDS ----------------
    const float4* xp = (const float4*)(x + ((size_t)bh * NL + l0) * ND);
    #pragma unroll
    for (int i = 0; i < 4; ++i) {
        int f4 = t + i * 256;
        float4 v = xp[f4];
        int row = f4 >> 4;
        int q = f4 & 15;
        float ss = v.x * v.x + v.y * v.y + v.z * v.z + v.w * v.w;
        ss += __shfl_xor(ss, 1); ss += __shfl_xor(ss, 2);
        ss += __shfl_xor(ss, 4); ss += __shfl_xor(ss, 8);
        float inv = 1.0f / fmaxf(sqrtf(ss), EPSV);
        if ((t & 15) == 0) sn2[row] = ss * inv * inv;   // == ||xn||^2 (1 unless tiny norm)
        float ax = v.x * inv, ay = v.y * inv, az = v.z * inv, aw = v.w * inv;
        int byte = row * 128 + ((q * 8) ^ ((row & 7) << 4));
        *(unsigned long long*)((char*)x_lds + byte) =
            (unsigned long long)bfpack(ax, ay) | ((unsigned long long)bfpack(az, aw) << 32);
    }
    __syncthreads();

    // ---------------- MFMA: 16 rows/wave x 512 cols ----------------
    const int wave = t >> 6, lane = t & 63;
    const int r16 = lane & 15, g = lane >> 4;

    const int arow = wave * 16 + r16;          // A frag: row = lane&15, k = g*8+j
    const char* xb = (const char*)x_lds + arow * 128;
    const int sw = (arow & 7) << 4;
    bf16x8 a0 = *(const bf16x8*)(xb + ((g * 16) ^ sw));
    bf16x8 a1 = *(const bf16x8*)(xb + ((64 + g * 16) ^ sw));

    float mx[4]; int mi[4];
    #pragma unroll
    for (int r = 0; r < 4; ++r) { mx[r] = -1e30f; mi[r] = 0; }

    const size_t obase = ((size_t)bh * NL + l0 + wave * 16) * NC;

    #pragma unroll 4
    for (int c0 = 0; c0 < NC; c0 += 16) {
        int brow = c0 + r16;                   // B frag: col = lane&15, k = g*8+j
        const char* mb = (const char*)m_lds + brow * 128;
        const int bsw = (brow & 7) << 4;
        bf16x8 b0 = *(const bf16x8*)(mb + ((g * 16) ^ bsw));
        bf16x8 b1 = *(const bf16x8*)(mb + ((64 + g * 16) ^ bsw));
        f32x4 acc = {0.f, 0.f, 0.f, 0.f};
        acc = __builtin_amdgcn_mfma_f32_16x16x32_bf16(a0, b0, acc, 0, 0, 0);
        acc = __builtin_amdgcn_mfma_f32_16x16x32_bf16(a1, b1, acc, 0, 0, 0);
        // C/D: lane holds D[g*4+r][c0+r16]
        #pragma unroll
        for (int r = 0; r < 4; ++r) {
            float v = acc[r];
            dists[obase + (size_t)(g * 4 + r) * NC + (c0 + r16)] = v;
            if (v > mx[r]) { mx[r] = v; mi[r] = c0 + r16; }
        }
    }

    // argmax reduce across the 16 lanes holding the same 4 rows (same g)
    #pragma unroll
    for (int s = 1; s < 16; s <<= 1) {
        #pragma unroll
        for (int r = 0; r < 4; ++r) {
            float ov = __shfl_xor(mx[r], s);
            int   oi = __shfl_xor(mi[r], s);
            if (ov > mx[r] || (ov == mx[r] && oi < mi[r])) { mx[r] = ov; mi[r] = oi; }
        }
    }

    // loss contribution: ||xn||^2 - 2*dmax + ||m_sel||^2, per row
    float sacc = 0.f;
    #pragma unroll
    for (int r = 0; r < 4; ++r)
        sacc += sn2[wave * 16 + g * 4 + r] - 2.f * mx[r] + msq[mi[r]];
    if (r16 != 0) sacc = 0.f;                  // one lane per 16-lane group contributes
    sacc += __shfl_xor(sacc, 16);
    sacc += __shfl_xor(sacc, 32);
    if (lane == 0) wsum[wave] = sacc;
    __syncthreads();
    if (t == 0) part[blockIdx.x] = wsum[0] + wsum[1] + wsum[2] + wsum[3];
}

__global__ __launch_bounds__(256) void loss_reduce(
    const float* __restrict__ part, float* __restrict__ loss)
{
    __shared__ float w[4];
    const int t = threadIdx.x;
    float s = 0.f;
    #pragma unroll
    for (int i = 0; i < NBLOCKS / 256; ++i) s += part[t + i * 256];
    s += __shfl_xor(s, 1);  s += __shfl_xor(s, 2);  s += __shfl_xor(s, 4);
    s += __shfl_xor(s, 8);  s += __shfl_xor(s, 16); s += __shfl_xor(s, 32);
    if ((t & 63) == 0) w[t >> 6] = s;
    __syncthreads();
    if (t == 0)
        loss[0] = (w[0] + w[1] + w[2] + w[3]) *
                  (COMMITV / (float)((size_t)NB * NH * NL * ND));
}

extern "C" void kernel_launch(void* const* d_in, const int* in_sizes, int n_in,
                              void* d_out, int out_size, void* d_ws, size_t ws_size,
                              hipStream_t stream) {
    const float* x = (const float*)d_in[0];
    const float* means = (const float*)d_in[1];
    float* dists = (float*)d_out;
    float* loss = dists + (size_t)NB * NH * NL * NC;  // second output, 1 elem
    float* part = (float*)d_ws;                       // 2048 fp32 partials

    dim3 grid(NBLOCKS);  // 2048
    dim3 block(256);
    kmeans_kernel<<<grid, block, 0, stream>>>(x, means, dists, part);
    loss_reduce<<<dim3(1), block, 0, stream>>>(part, loss);
}

// Round 5
// 330.161 us; speedup vs baseline: 1.1695x; 1.0972x over previous
//
#include <hip/hip_runtime.h>
#include <hip/hip_bf16.h>

#define NB 4
#define NH 8
#define NL 4096
#define ND 64
#define NC 512
#define TILE_L 128                           // rows per block (8 waves x 16)
#define NBLOCKS (NB * NH * (NL / TILE_L))    // 1024
#define EPSV 1e-12f
#define COMMITV 0.0001f

typedef __attribute__((ext_vector_type(8))) short bf16x8;
typedef __attribute__((ext_vector_type(4))) float f32x4;

// round-to-nearest-even pack of two fp32 -> packed 2x bf16
__device__ __forceinline__ unsigned bfpack(float a, float b) {
    unsigned ua = __float_as_uint(a);
    unsigned ub = __float_as_uint(b);
    ua = (ua + 0x7fffu + ((ua >> 16) & 1u)) >> 16;
    ub = (ub + 0x7fffu + ((ub >> 16) & 1u)) & 0xffff0000u;
    return (ua & 0xffffu) | ub;
}

union bfrag { unsigned u[4]; bf16x8 v; };

__global__ __launch_bounds__(512, 4) void kmeans_kernel(
    const float* __restrict__ x, const float* __restrict__ means,
    float* __restrict__ dists, float* __restrict__ part)
{
    // swizzled bf16 means tile: row stride 128B, byte col offset ^= (row&7)<<4
    __shared__ alignas(16) unsigned short m_lds[NC * ND];      // 64 KB
    __shared__ float msq[NC];                                  // 2 KB fp32 ||means_c||^2
    __shared__ float wsum[8];

    const int t = threadIdx.x;
    const int ltiles = NL / TILE_L;            // 32
    const int bh = blockIdx.x / ltiles;        // 0..31  (b*8+h)
    const int l0 = (blockIdx.x % ltiles) * TILE_L;
    const int h  = bh & (NH - 1);

    // ---------------- stage means[h] -> bf16 LDS (+ fp32 msq) ----------------
    const float4* mp = (const float4*)(means + (size_t)h * NC * ND);
    #pragma unroll 4
    for (int i = 0; i < 16; ++i) {
        int f4 = t + i * 512;                  // float4 index, 16 per row
        float4 v = mp[f4];
        int row = f4 >> 4;
        int q = f4 & 15;
        float ss = v.x * v.x + v.y * v.y + v.z * v.z + v.w * v.w;
        ss += __shfl_xor(ss, 1); ss += __shfl_xor(ss, 2);
        ss += __shfl_xor(ss, 4); ss += __shfl_xor(ss, 8);
        if ((t & 15) == 0) msq[row] = ss;
        unsigned lo = bfpack(v.x, v.y), hi = bfpack(v.z, v.w);
        int byte = row * 128 + ((q * 8) ^ ((row & 7) << 4));
        *(unsigned long long*)((char*)m_lds + byte) =
            (unsigned long long)lo | ((unsigned long long)hi << 32);
    }

    // ---------------- x rows: load + normalize + A-frags entirely in registers ----------------
    const int wave = t >> 6, lane = t & 63;
    const int r16 = lane & 15, g = lane >> 4;

    // A frag layout for mfma_f32_16x16x32_bf16: row = lane&15, k = (lane>>4)*8 + j
    // a0 covers k in [0,32): elems x[row][g*8 .. g*8+8)   = float4 idx g*2, g*2+1
    // a1 covers k in [32,64): elems x[row][32+g*8 .. +8)  = float4 idx 8+g*2, 8+g*2+1
    const int xrow = l0 + wave * 16 + r16;
    const float4* xr = (const float4*)(x + ((size_t)bh * NL + xrow) * ND);
    float4 v0 = xr[g * 2], v1 = xr[g * 2 + 1];
    float4 v2 = xr[8 + g * 2], v3 = xr[8 + g * 2 + 1];

    float ss = v0.x*v0.x + v0.y*v0.y + v0.z*v0.z + v0.w*v0.w
             + v1.x*v1.x + v1.y*v1.y + v1.z*v1.z + v1.w*v1.w
             + v2.x*v2.x + v2.y*v2.y + v2.z*v2.z + v2.w*v2.w
             + v3.x*v3.x + v3.y*v3.y + v3.z*v3.z + v3.w*v3.w;
    ss += __shfl_xor(ss, 16);
    ss += __shfl_xor(ss, 32);                  // full 64-elem row sum-of-squares
    const float inv = 1.0f / fmaxf(sqrtf(ss), EPSV);
    const float sn2 = ss * inv * inv;          // ||xn||^2 (1 unless tiny norm)

    bfrag a0f, a1f;
    a0f.u[0] = bfpack(v0.x * inv, v0.y * inv); a0f.u[1] = bfpack(v0.z * inv, v0.w * inv);
    a0f.u[2] = bfpack(v1.x * inv, v1.y * inv); a0f.u[3] = bfpack(v1.z * inv, v1.w * inv);
    a1f.u[0] = bfpack(v2.x * inv, v2.y * inv); a1f.u[1] = bfpack(v2.z * inv, v2.w * inv);
    a1f.u[2] = bfpack(v3.x * inv, v3.y * inv); a1f.u[3] = bfpack(v3.z * inv, v3.w * inv);
    const bf16x8 a0 = a0f.v, a1 = a1f.v;

    __syncthreads();

    // ---------------- MFMA: 16 rows/wave x 512 cols ----------------
    float mx[4]; int mi[4];
    #pragma unroll
    for (int r = 0; r < 4; ++r) { mx[r] = -1e30f; mi[r] = 0; }

    const size_t obase = ((size_t)bh * NL + l0 + wave * 16) * NC;

    #pragma unroll 4
    for (int c0 = 0; c0 < NC; c0 += 16) {
        int brow = c0 + r16;                   // B frag: col = lane&15, k = g*8+j
        const char* mb = (const char*)m_lds + brow * 128;
        const int bsw = (brow & 7) << 4;
        bf16x8 b0 = *(const bf16x8*)(mb + ((g * 16) ^ bsw));
        bf16x8 b1 = *(const bf16x8*)(mb + ((64 + g * 16) ^ bsw));
        f32x4 acc = {0.f, 0.f, 0.f, 0.f};
        acc = __builtin_amdgcn_mfma_f32_16x16x32_bf16(a0, b0, acc, 0, 0, 0);
        acc = __builtin_amdgcn_mfma_f32_16x16x32_bf16(a1, b1, acc, 0, 0, 0);
        // C/D: lane holds D[g*4+r][c0+r16]
        #pragma unroll
        for (int r = 0; r < 4; ++r) {
            float v = acc[r];
            __builtin_nontemporal_store(v,
                &dists[obase + (size_t)(g * 4 + r) * NC + (c0 + r16)]);
            if (v > mx[r]) { mx[r] = v; mi[r] = c0 + r16; }
        }
    }

    // argmax reduce across the 16 lanes holding the same 4 rows (same g)
    #pragma unroll
    for (int s = 1; s < 16; s <<= 1) {
        #pragma unroll
        for (int r = 0; r < 4; ++r) {
            float ov = __shfl_xor(mx[r], s);
            int   oi = __shfl_xor(mi[r], s);
            if (ov > mx[r] || (ov == mx[r] && oi < mi[r])) { mx[r] = ov; mi[r] = oi; }
        }
    }

    // loss contribution: ||xn||^2 - 2*dmax + ||m_sel||^2, per row
    float sacc = 0.f;
    #pragma unroll
    for (int r = 0; r < 4; ++r) {
        float s2 = __shfl(sn2, g * 4 + r);     // lane (g*4+r) holds row w*16+(g*4+r)
        sacc += s2 - 2.f * mx[r] + msq[mi[r]];
    }
    if (r16 != 0) sacc = 0.f;                  // one lane per 16-lane group contributes
    sacc += __shfl_xor(sacc, 16);
    sacc += __shfl_xor(sacc, 32);
    if (lane == 0) wsum[wave] = sacc;
    __syncthreads();
    if (t == 0) {
        float s = 0.f;
        #pragma unroll
        for (int w = 0; w < 8; ++w) s += wsum[w];
        part[blockIdx.x] = s;
    }
}

__global__ __launch_bounds__(256) void loss_reduce(
    const float* __restrict__ part, float* __restrict__ loss)
{
    __shared__ float w[4];
    const int t = threadIdx.x;
    float s = 0.f;
    #pragma unroll
    for (int i = 0; i < NBLOCKS / 256; ++i) s += part[t + i * 256];
    s += __shfl_xor(s, 1);  s += __shfl_xor(s, 2);  s += __shfl_xor(s, 4);
    s += __shfl_xor(s, 8);  s += __shfl_xor(s, 16); s += __shfl_xor(s, 32);
    if ((t & 63) == 0) w[t >> 6] = s;
    __syncthreads();
    if (t == 0)
        loss[0] = (w[0] + w[1] + w[2] + w[3]) *
                  (COMMITV / (float)((size_t)NB * NH * NL * ND));
}

extern "C" void kernel_launch(void* const* d_in, const int* in_sizes, int n_in,
                              void* d_out, int out_size, void* d_ws, size_t ws_size,
                              hipStream_t stream) {
    const float* x = (const float*)d_in[0];
    const float* means = (const float*)d_in[1];
    float* dists = (float*)d_out;
    float* loss = dists + (size_t)NB * NH * NL * NC;  // second output, 1 elem
    float* part = (float*)d_ws;                       // 1024 fp32 partials

    kmeans_kernel<<<dim3(NBLOCKS), dim3(512), 0, stream>>>(x, means, dists, part);
    loss_reduce<<<dim3(1), dim3(256), 0, stream>>>(part, loss);
}

// Round 6
// 312.398 us; speedup vs baseline: 1.2360x; 1.0569x over previous
//
#include <hip/hip_runtime.h>
#include <hip/hip_bf16.h>

#define NB 4
#define NH 8
#define NL 4096
#define ND 64
#define NC 512
#define TILE_L 256                           // rows per block (8 waves x 32)
#define NBLOCKS (NB * NH * (NL / TILE_L))    // 512
#define EPSV 1e-12f
#define COMMITV 0.0001f

typedef __attribute__((ext_vector_type(8))) short bf16x8;
typedef __attribute__((ext_vector_type(16))) float f32x16;

// round-to-nearest-even pack of two fp32 -> packed 2x bf16
__device__ __forceinline__ unsigned bfpack(float a, float b) {
    unsigned ua = __float_as_uint(a);
    unsigned ub = __float_as_uint(b);
    ua = (ua + 0x7fffu + ((ua >> 16) & 1u)) >> 16;
    ub = (ub + 0x7fffu + ((ub >> 16) & 1u)) & 0xffff0000u;
    return (ua & 0xffffu) | ub;
}

union bfrag { unsigned u[4]; bf16x8 v; };

__global__ __launch_bounds__(512, 4) void kmeans_kernel(
    const float* __restrict__ x, const float* __restrict__ means,
    float* __restrict__ dists, float* __restrict__ part)
{
    // swizzled bf16 means tile: row stride 128B, byte col offset ^= (row&7)<<4
    __shared__ alignas(16) unsigned short m_lds[NC * ND];      // 64 KB
    __shared__ float msq[NC];                                  // 2 KB fp32 ||means_c||^2
    __shared__ float wsum[8];

    const int t = threadIdx.x;
    const int ltiles = NL / TILE_L;            // 16
    const int bh = blockIdx.x / ltiles;        // 0..31  (b*8+h)
    const int l0 = (blockIdx.x % ltiles) * TILE_L;
    const int h  = bh & (NH - 1);

    // ---------------- stage means[h] -> bf16 LDS (+ fp32 msq) ----------------
    const float4* mp = (const float4*)(means + (size_t)h * NC * ND);
    #pragma unroll 4
    for (int i = 0; i < 16; ++i) {
        int f4 = t + i * 512;                  // float4 index, 16 per row
        float4 v = mp[f4];
        int row = f4 >> 4;
        int q = f4 & 15;
        float ss = v.x * v.x + v.y * v.y + v.z * v.z + v.w * v.w;
        ss += __shfl_xor(ss, 1); ss += __shfl_xor(ss, 2);
        ss += __shfl_xor(ss, 4); ss += __shfl_xor(ss, 8);
        if ((t & 15) == 0) msq[row] = ss;
        unsigned lo = bfpack(v.x, v.y), hi2 = bfpack(v.z, v.w);
        int byte = row * 128 + ((q * 8) ^ ((row & 7) << 4));
        *(unsigned long long*)((char*)m_lds + byte) =
            (unsigned long long)lo | ((unsigned long long)hi2 << 32);
    }

    // ---------------- x rows: load + normalize + A-frags in registers ----------------
    const int wave = t >> 6, lane = t & 63;
    const int l31 = lane & 31, hi = lane >> 5;

    // A frag for mfma_f32_32x32x16_bf16 (chained kk=0..3 over K=64):
    //   row = lane&31, k = (lane>>5)*8 + j + 16*kk
    //   lane needs x[row][16kk+8hi .. +8) = float4 idx 4kk+2hi, 4kk+2hi+1
    const int xrow = l0 + wave * 32 + l31;
    const float4* xr = (const float4*)(x + ((size_t)bh * NL + xrow) * ND);
    float4 xv[8];
    #pragma unroll
    for (int kk = 0; kk < 4; ++kk) {
        xv[2 * kk]     = xr[4 * kk + 2 * hi];
        xv[2 * kk + 1] = xr[4 * kk + 2 * hi + 1];
    }
    float ss = 0.f;
    #pragma unroll
    for (int i = 0; i < 8; ++i)
        ss += xv[i].x * xv[i].x + xv[i].y * xv[i].y
            + xv[i].z * xv[i].z + xv[i].w * xv[i].w;
    ss += __shfl_xor(ss, 32);                  // full 64-elem row sum-of-squares
    const float inv = 1.0f / fmaxf(sqrtf(ss), EPSV);
    const float sn2 = ss * inv * inv;          // ||xn||^2 (1 unless tiny norm)

    bfrag a0, a1, a2, a3;
    #pragma unroll
    for (int j = 0; j < 2; ++j) {
        a0.u[2*j] = bfpack(xv[j].x * inv, xv[j].y * inv);
        a0.u[2*j+1] = bfpack(xv[j].z * inv, xv[j].w * inv);
        a1.u[2*j] = bfpack(xv[2+j].x * inv, xv[2+j].y * inv);
        a1.u[2*j+1] = bfpack(xv[2+j].z * inv, xv[2+j].w * inv);
        a2.u[2*j] = bfpack(xv[4+j].x * inv, xv[4+j].y * inv);
        a2.u[2*j+1] = bfpack(xv[4+j].z * inv, xv[4+j].w * inv);
        a3.u[2*j] = bfpack(xv[6+j].x * inv, xv[6+j].y * inv);
        a3.u[2*j+1] = bfpack(xv[6+j].z * inv, xv[6+j].w * inv);
    }
    const bf16x8 af0 = a0.v, af1 = a1.v, af2 = a2.v, af3 = a3.v;

    __syncthreads();

    // ---------------- MFMA: 32 rows/wave x 512 cols, 32x32 tiles ----------------
    float mx[16]; int mi[16];
    #pragma unroll
    for (int r = 0; r < 16; ++r) { mx[r] = -1e30f; mi[r] = 0; }

    const size_t obase = ((size_t)bh * NL + l0 + wave * 32) * NC;

    for (int c0 = 0; c0 < NC; c0 += 32) {
        int brow = c0 + l31;                   // B: col = lane&31, k = hi*8+j+16kk
        const char* mb = (const char*)m_lds + brow * 128;
        const int bsw = (brow & 7) << 4;
        bf16x8 b0 = *(const bf16x8*)(mb + ((0  + 16 * hi) ^ bsw));
        bf16x8 b1 = *(const bf16x8*)(mb + ((32 + 16 * hi) ^ bsw));
        bf16x8 b2 = *(const bf16x8*)(mb + ((64 + 16 * hi) ^ bsw));
        bf16x8 b3 = *(const bf16x8*)(mb + ((96 + 16 * hi) ^ bsw));
        f32x16 acc = {};
        acc = __builtin_amdgcn_mfma_f32_32x32x16_bf16(af0, b0, acc, 0, 0, 0);
        acc = __builtin_amdgcn_mfma_f32_32x32x16_bf16(af1, b1, acc, 0, 0, 0);
        acc = __builtin_amdgcn_mfma_f32_32x32x16_bf16(af2, b2, acc, 0, 0, 0);
        acc = __builtin_amdgcn_mfma_f32_32x32x16_bf16(af3, b3, acc, 0, 0, 0);
        // C/D (verified m74/m101): col = lane&31, row = (r&3)+8*(r>>2)+4*hi
        #pragma unroll
        for (int r = 0; r < 16; ++r) {
            float v = acc[r];
            int row = (r & 3) + 8 * (r >> 2) + 4 * hi;
            __builtin_nontemporal_store(v,
                &dists[obase + (size_t)row * NC + (c0 + l31)]);
            if (v > mx[r]) { mx[r] = v; mi[r] = c0 + l31; }
        }
    }

    // argmax reduce across 32 lanes of the same hi-half (same row set)
    #pragma unroll
    for (int s = 1; s < 32; s <<= 1) {
        #pragma unroll
        for (int r = 0; r < 16; ++r) {
            float ov = __shfl_xor(mx[r], s);
            int   oi = __shfl_xor(mi[r], s);
            if (ov > mx[r] || (ov == mx[r] && oi < mi[r])) { mx[r] = ov; mi[r] = oi; }
        }
    }

    // loss: ||xn||^2 - 2*dmax + ||m_sel||^2 per row; rows of hi=0/1 are disjoint
    float sacc = 0.f;
    #pragma unroll
    for (int r = 0; r < 16; ++r) {
        int rl = (r & 3) + 8 * (r >> 2) + 4 * hi;   // local row 0..31
        float s2 = __shfl(sn2, rl);                 // lane rl holds that row's sn2
        sacc += s2 - 2.f * mx[r] + msq[mi[r]];
    }
    if (l31 != 0) sacc = 0.f;                  // lanes 0 and 32 contribute
    sacc += __shfl_xor(sacc, 32);
    if (lane == 0) wsum[wave] = sacc;
    __syncthreads();
    if (t == 0) {
        float s = 0.f;
        #pragma unroll
        for (int w = 0; w < 8; ++w) s += wsum[w];
        part[blockIdx.x] = s;
    }
}

__global__ __launch_bounds__(256) void loss_reduce(
    const float* __restrict__ part, float* __restrict__ loss)
{
    __shared__ float w[4];
    const int t = threadIdx.x;
    float s = 0.f;
    #pragma unroll
    for (int i = 0; i < NBLOCKS / 256; ++i) s += part[t + i * 256];
    s += __shfl_xor(s, 1);  s += __shfl_xor(s, 2);  s += __shfl_xor(s, 4);
    s += __shfl_xor(s, 8);  s += __shfl_xor(s, 16); s += __shfl_xor(s, 32);
    if ((t & 63) == 0) w[t >> 6] = s;
    __syncthreads();
    if (t == 0)
        loss[0] = (w[0] + w[1] + w[2] + w[3]) *
                  (COMMITV / (float)((size_t)NB * NH * NL * ND));
}

extern "C" void kernel_launch(void* const* d_in, const int* in_sizes, int n_in,
                              void* d_out, int out_size, void* d_ws, size_t ws_size,
                              hipStream_t stream) {
    const float* x = (const float*)d_in[0];
    const float* means = (const float*)d_in[1];
    float* dists = (float*)d_out;
    float* loss = dists + (size_t)NB * NH * NL * NC;  // second output, 1 elem
    float* part = (float*)d_ws;                       // 512 fp32 partials

    kmeans_kernel<<<dim3(NBLOCKS), dim3(512), 0, stream>>>(x, means, dists, part);
    loss_reduce<<<dim3(1), dim3(256), 0, stream>>>(part, loss);
}